// Round 1
// baseline (2396.674 us; speedup 1.0000x reference)
//
#include <hip/hip_runtime.h>
#include <math.h>

#define BATCH 4
#define CH    256
#define NSP   4096          // 16*16*16
#define NGRP  32
#define EPS_GN 1e-5f

// ws layout (floats): q | k | v | h  (each B*N*C = 4,194,304) | stats (B*G*2)
#define WS_Q 0
#define WS_K 4194304
#define WS_V 8388608
#define WS_H 12582912
#define WS_STATS 16777216

// ---------------------------------------------------------------------------
// Kernel 1: QKV projection.  out[b][n][o] = sum_c w[o][c]*x[b][c][n] + bias[o]
// x: [B][C][N] fp32 ; out: [B][N][C] fp32
// grid (N/64, C/64, B*3), block 256
__global__ __launch_bounds__(256) void qkv_proj_kernel(
    const float* __restrict__ x,
    const float* __restrict__ wq, const float* __restrict__ bq,
    const float* __restrict__ wk, const float* __restrict__ bk,
    const float* __restrict__ wv, const float* __restrict__ bv,
    float* __restrict__ qo, float* __restrict__ ko, float* __restrict__ vo)
{
    const int p = blockIdx.z % 3;
    const int b = blockIdx.z / 3;
    const float* __restrict__ w    = (p == 0) ? wq : (p == 1) ? wk : wv;
    const float* __restrict__ bias = (p == 0) ? bq : (p == 1) ? bk : bv;
    float* __restrict__ out        = (p == 0) ? qo : (p == 1) ? ko : vo;

    const int on = blockIdx.x * 64;
    const int oo = blockIdx.y * 64;
    const int t  = threadIdx.x;
    const int ni = t & 15, oi = t >> 4;

    __shared__ float Xs[32][68];   // [c][n]
    __shared__ float Ws[32][68];   // [c][o]  (stored transposed)

    float acc[4][4];
    #pragma unroll
    for (int i = 0; i < 4; ++i)
        #pragma unroll
        for (int j = 0; j < 4; ++j) acc[i][j] = 0.f;

    for (int ct = 0; ct < CH; ct += 32) {
        {   // X tile: 32 c-rows x 64 n-cols (coalesced along n)
            const int col = t & 63, r0 = t >> 6;   // r0 in 0..3
            #pragma unroll
            for (int r = 0; r < 8; ++r)
                Xs[r0 + 4*r][col] = x[((size_t)b*CH + ct + r0 + 4*r)*NSP + on + col];
        }
        {   // W tile: 64 o-rows x 32 c-cols, transposed store (coalesced along c)
            const int col = t & 31, r0 = t >> 5;   // r0 in 0..7
            #pragma unroll
            for (int r = 0; r < 8; ++r)
                Ws[col][r0 + 8*r] = w[(oo + r0 + 8*r)*CH + ct + col];
        }
        __syncthreads();
        #pragma unroll
        for (int cc = 0; cc < 32; ++cc) {
            const float4 xv  = *(const float4*)&Xs[cc][ni*4];
            const float4 wv4 = *(const float4*)&Ws[cc][oi*4];
            const float xr[4] = {xv.x, xv.y, xv.z, xv.w};
            const float wr[4] = {wv4.x, wv4.y, wv4.z, wv4.w};
            #pragma unroll
            for (int i = 0; i < 4; ++i)
                #pragma unroll
                for (int j = 0; j < 4; ++j) acc[i][j] += wr[i] * xr[j];
        }
        __syncthreads();
    }

    // write out[b][n][o]: contiguous float4 along o per n-row
    const float4 bb = *(const float4*)&bias[oo + oi*4];
    const float br[4] = {bb.x, bb.y, bb.z, bb.w};
    #pragma unroll
    for (int j = 0; j < 4; ++j) {
        const int n = on + ni*4 + j;
        float4 o4;
        o4.x = acc[0][j] + br[0];
        o4.y = acc[1][j] + br[1];
        o4.z = acc[2][j] + br[2];
        o4.w = acc[3][j] + br[3];
        *(float4*)&out[((size_t)b*NSP + n)*CH + oo + oi*4] = o4;
    }
}

// ---------------------------------------------------------------------------
// Kernel 2: flash attention, fp32.  q,k,v: [B][N][C]; h: [B][N][C]
// grid (N/64, B), block 256.  TQ=64 rows per block, TK=32 keys per tile.
__global__ __launch_bounds__(256) void attn_kernel(
    const float* __restrict__ q, const float* __restrict__ k,
    const float* __restrict__ v, float* __restrict__ h)
{
    __shared__ float Qs[64][260];
    __shared__ float Ks[32][260];
    __shared__ float Vs[32][260];
    __shared__ float Ss[64][36];
    __shared__ float Mrow[64], Lrow[64], Scal[64];
    __shared__ float Rmax[64][4], Rsum[64][4];

    const int t   = threadIdx.x;
    const int b   = blockIdx.y;
    const int qn0 = blockIdx.x * 64;

    // load Q tile (contiguous 64 KB)
    const float* __restrict__ qb = q + ((size_t)b*NSP + qn0)*CH;
    #pragma unroll
    for (int it = 0; it < 16; ++it) {
        const int qi = t + 256*it;            // quad idx 0..4095
        const int row = qi >> 6, cq = (qi & 63) * 4;
        *(float4*)&Qs[row][cq] = *(const float4*)&qb[row*CH + cq];
    }
    if (t < 64) { Mrow[t] = -3.0e38f; Lrow[t] = 0.f; }

    const int ti = t & 15;    // S rows ti+16j; PV rows same; output rows same
    const int tm = t >> 4;    // S cols 2tm, 2tm+1
    const int r  = t >> 2;    // softmax row
    const int qd = t & 3;     // softmax quarter (8 m's each)
    const int cg = t >> 4;    // PV col group: cols 4cg + 64cj

    float4 acc4[4][4];
    #pragma unroll
    for (int ri = 0; ri < 4; ++ri)
        #pragma unroll
        for (int cj = 0; cj < 4; ++cj) acc4[ri][cj] = make_float4(0.f, 0.f, 0.f, 0.f);

    for (int kt = 0; kt < NSP; kt += 32) {
        __syncthreads();   // (A) previous PV done; K/V/Ss reusable
        const float* __restrict__ kb = k + ((size_t)b*NSP + kt)*CH;
        const float* __restrict__ vb = v + ((size_t)b*NSP + kt)*CH;
        #pragma unroll
        for (int it = 0; it < 8; ++it) {
            const int qi = t + 256*it;        // quad idx 0..2047
            const int row = qi >> 6, cq = (qi & 63) * 4;
            *(float4*)&Ks[row][cq] = *(const float4*)&kb[row*CH + cq];
            *(float4*)&Vs[row][cq] = *(const float4*)&vb[row*CH + cq];
        }
        __syncthreads();   // (B) K/V ready

        // S = Q K^T   (rows i = ti+16j, cols m = 2tm, 2tm+1)
        float s0[4] = {0.f,0.f,0.f,0.f}, s1[4] = {0.f,0.f,0.f,0.f};
        #pragma unroll 8
        for (int cc = 0; cc < CH; cc += 4) {
            const float4 k0 = *(const float4*)&Ks[2*tm][cc];
            const float4 k1 = *(const float4*)&Ks[2*tm + 1][cc];
            #pragma unroll
            for (int j = 0; j < 4; ++j) {
                const float4 qv = *(const float4*)&Qs[ti + 16*j][cc];
                s0[j] += qv.x*k0.x + qv.y*k0.y + qv.z*k0.z + qv.w*k0.w;
                s1[j] += qv.x*k1.x + qv.y*k1.y + qv.z*k1.z + qv.w*k1.w;
            }
        }
        #pragma unroll
        for (int j = 0; j < 4; ++j) {
            Ss[ti + 16*j][2*tm]     = s0[j];
            Ss[ti + 16*j][2*tm + 1] = s1[j];
        }
        __syncthreads();   // (C) S ready

        // online softmax, 4 threads per row
        float pm = -3.0e38f;
        #pragma unroll
        for (int mm = 0; mm < 8; ++mm) pm = fmaxf(pm, Ss[r][qd*8 + mm]);
        Rmax[r][qd] = pm;
        __syncthreads();   // (D)

        const float tmax = fmaxf(fmaxf(Rmax[r][0], Rmax[r][1]),
                                 fmaxf(Rmax[r][2], Rmax[r][3]));
        const float mold = Mrow[r];
        const float nm   = fmaxf(mold, tmax);
        float ps = 0.f;
        #pragma unroll
        for (int mm = 0; mm < 8; ++mm) {
            const float pe = __expf(Ss[r][qd*8 + mm] - nm);
            Ss[r][qd*8 + mm] = pe;
            ps += pe;
        }
        Rsum[r][qd] = ps;
        __syncthreads();   // (E)
        if (qd == 0) {
            const float sc = __expf(mold - nm);
            Lrow[r] = Lrow[r]*sc + Rsum[r][0] + Rsum[r][1] + Rsum[r][2] + Rsum[r][3];
            Mrow[r] = nm;
            Scal[r] = sc;
        }
        __syncthreads();   // (F)

        // rescale accumulator + PV accumulate
        float scl[4];
        #pragma unroll
        for (int ri = 0; ri < 4; ++ri) scl[ri] = Scal[ti + 16*ri];
        #pragma unroll
        for (int ri = 0; ri < 4; ++ri)
            #pragma unroll
            for (int cj = 0; cj < 4; ++cj) {
                acc4[ri][cj].x *= scl[ri];
                acc4[ri][cj].y *= scl[ri];
                acc4[ri][cj].z *= scl[ri];
                acc4[ri][cj].w *= scl[ri];
            }
        #pragma unroll 4
        for (int m = 0; m < 32; ++m) {
            float pr[4];
            #pragma unroll
            for (int ri = 0; ri < 4; ++ri) pr[ri] = Ss[ti + 16*ri][m];
            #pragma unroll
            for (int cj = 0; cj < 4; ++cj) {
                const float4 vv = *(const float4*)&Vs[m][cg*4 + 64*cj];
                #pragma unroll
                for (int ri = 0; ri < 4; ++ri) {
                    acc4[ri][cj].x += pr[ri]*vv.x;
                    acc4[ri][cj].y += pr[ri]*vv.y;
                    acc4[ri][cj].z += pr[ri]*vv.z;
                    acc4[ri][cj].w += pr[ri]*vv.w;
                }
            }
        }
    }

    float inv[4];
    #pragma unroll
    for (int ri = 0; ri < 4; ++ri) inv[ri] = 1.f / Lrow[ti + 16*ri];
    float* __restrict__ hb = h + ((size_t)b*NSP + qn0)*CH;
    #pragma unroll
    for (int ri = 0; ri < 4; ++ri)
        #pragma unroll
        for (int cj = 0; cj < 4; ++cj) {
            float4 o4;
            o4.x = acc4[ri][cj].x * inv[ri];
            o4.y = acc4[ri][cj].y * inv[ri];
            o4.z = acc4[ri][cj].z * inv[ri];
            o4.w = acc4[ri][cj].w * inv[ri];
            *(float4*)&hb[(ti + 16*ri)*CH + cg*4 + 64*cj] = o4;
        }
}

// ---------------------------------------------------------------------------
// Kernel 3: y[b][o][n] = sum_c wo[o][c]*h[b][n][c] + bo[o] + x[b][o][n]
// also accumulates per-(b,group) sum/sumsq via atomics.
// grid (N/64, C/64, B), block 256
__global__ __launch_bounds__(256) void oproj_kernel(
    const float* __restrict__ h, const float* __restrict__ wo,
    const float* __restrict__ bo, const float* __restrict__ x,
    float* __restrict__ y, float* __restrict__ stats)
{
    const int b  = blockIdx.z;
    const int on = blockIdx.x * 64;
    const int oo = blockIdx.y * 64;
    const int t  = threadIdx.x;
    const int ni = t & 15, oi = t >> 4;

    __shared__ float Hs[32][68];   // [c][n]
    __shared__ float Ws[32][68];   // [c][o]

    float acc[4][4];
    #pragma unroll
    for (int i = 0; i < 4; ++i)
        #pragma unroll
        for (int j = 0; j < 4; ++j) acc[i][j] = 0.f;

    for (int ct = 0; ct < CH; ct += 32) {
        {   // H tile: rows n (64), cols c (32) -> transposed store [c][n]
            const int col = t & 31, r0 = t >> 5;
            #pragma unroll
            for (int rr = 0; rr < 8; ++rr)
                Hs[col][r0 + 8*rr] = h[((size_t)b*NSP + on + r0 + 8*rr)*CH + ct + col];
        }
        {   // W tile transposed
            const int col = t & 31, r0 = t >> 5;
            #pragma unroll
            for (int rr = 0; rr < 8; ++rr)
                Ws[col][r0 + 8*rr] = wo[(oo + r0 + 8*rr)*CH + ct + col];
        }
        __syncthreads();
        #pragma unroll
        for (int cc = 0; cc < 32; ++cc) {
            const float4 hv  = *(const float4*)&Hs[cc][ni*4];
            const float4 wv4 = *(const float4*)&Ws[cc][oi*4];
            const float hr[4] = {hv.x, hv.y, hv.z, hv.w};
            const float wr[4] = {wv4.x, wv4.y, wv4.z, wv4.w};
            #pragma unroll
            for (int i = 0; i < 4; ++i)
                #pragma unroll
                for (int j = 0; j < 4; ++j) acc[i][j] += wr[i] * hr[j];
        }
        __syncthreads();
    }

    float s = 0.f, sq = 0.f;
    #pragma unroll
    for (int i = 0; i < 4; ++i) {
        const int o = oo + oi*4 + i;
        const float bb = bo[o];
        const size_t base = ((size_t)b*CH + o)*NSP + on + ni*4;
        const float4 xv = *(const float4*)&x[base];
        float4 o4;
        o4.x = acc[i][0] + bb + xv.x;
        o4.y = acc[i][1] + bb + xv.y;
        o4.z = acc[i][2] + bb + xv.z;
        o4.w = acc[i][3] + bb + xv.w;
        *(float4*)&y[base] = o4;
        s  += o4.x + o4.y + o4.z + o4.w;
        sq += o4.x*o4.x + o4.y*o4.y + o4.z*o4.z + o4.w*o4.w;
    }
    // thread's 4 o-rows lie in one group (4-aligned run inside 8-aligned group)
    #pragma unroll
    for (int off = 8; off > 0; off >>= 1) {
        s  += __shfl_down(s, off, 16);
        sq += __shfl_down(sq, off, 16);
    }
    if (ni == 0) {
        const int gg = (oo >> 3) + (oi >> 1);
        atomicAdd(&stats[((size_t)b*NGRP + gg)*2 + 0], s);
        atomicAdd(&stats[((size_t)b*NGRP + gg)*2 + 1], sq);
    }
}

// ---------------------------------------------------------------------------
// Kernel 4: GroupNorm finalize + swish, in-place on y (= d_out).
// grid (B*G), block 256; each block handles 8 rows x 4096 = 32768 contiguous floats
__global__ __launch_bounds__(256) void gn_swish_kernel(
    float* __restrict__ y, const float* __restrict__ stats,
    const float* __restrict__ gamma, const float* __restrict__ beta)
{
    const int bg = blockIdx.x;
    const int b = bg >> 5, g = bg & 31;
    const float s  = stats[bg*2 + 0];
    const float sq = stats[bg*2 + 1];
    const float inv_n = 1.f / 32768.f;
    const float mu  = s * inv_n;
    const float var = sq * inv_n - mu*mu;
    const float rs  = rsqrtf(var + EPS_GN);
    float* __restrict__ base = y + ((size_t)b*CH + g*8)*NSP;
    const int t = threadIdx.x;
    #pragma unroll 4
    for (int it = 0; it < 32; ++it) {
        const int qi = t + 256*it;            // quad idx 0..8191
        const int o8 = qi >> 10;              // row within group
        const float ga = gamma[g*8 + o8] * rs;
        const float be = beta[g*8 + o8];
        float4 yv = *(const float4*)&base[qi*4];
        float yn;
        yn = (yv.x - mu)*ga + be; yv.x = yn / (1.f + __expf(-yn));
        yn = (yv.y - mu)*ga + be; yv.y = yn / (1.f + __expf(-yn));
        yn = (yv.z - mu)*ga + be; yv.z = yn / (1.f + __expf(-yn));
        yn = (yv.w - mu)*ga + be; yv.w = yn / (1.f + __expf(-yn));
        *(float4*)&base[qi*4] = yv;
    }
}

// ---------------------------------------------------------------------------
extern "C" void kernel_launch(void* const* d_in, const int* in_sizes, int n_in,
                              void* d_out, int out_size, void* d_ws, size_t ws_size,
                              hipStream_t stream)
{
    const float* x     = (const float*)d_in[0];
    const float* wq    = (const float*)d_in[1];
    const float* bq    = (const float*)d_in[2];
    const float* wk    = (const float*)d_in[3];
    const float* bk    = (const float*)d_in[4];
    const float* wv    = (const float*)d_in[5];
    const float* bv    = (const float*)d_in[6];
    const float* wo    = (const float*)d_in[7];
    const float* bo    = (const float*)d_in[8];
    const float* gamma = (const float*)d_in[9];
    const float* beta  = (const float*)d_in[10];

    float* out = (float*)d_out;
    float* ws  = (float*)d_ws;
    float* q     = ws + WS_Q;
    float* k     = ws + WS_K;
    float* v     = ws + WS_V;
    float* h     = ws + WS_H;
    float* stats = ws + WS_STATS;

    hipMemsetAsync(stats, 0, BATCH*NGRP*2*sizeof(float), stream);

    dim3 g1(NSP/64, CH/64, BATCH*3);
    qkv_proj_kernel<<<g1, 256, 0, stream>>>(x, wq, bq, wk, bk, wv, bv, q, k, v);

    dim3 g2(NSP/64, BATCH);
    attn_kernel<<<g2, 256, 0, stream>>>(q, k, v, h);

    dim3 g3(NSP/64, CH/64, BATCH);
    oproj_kernel<<<g3, 256, 0, stream>>>(h, wo, bo, x, out, stats);

    gn_swish_kernel<<<BATCH*NGRP, 256, 0, stream>>>(out, stats, gamma, beta);
}

// Round 2
// 445.380 us; speedup vs baseline: 5.3812x; 5.3812x over previous
//
#include <hip/hip_runtime.h>
#include <math.h>

#define BATCH 4
#define CH    256
#define NSP   4096          // 16*16*16
#define NGRP  32
#define EPS_GN 1e-5f

typedef _Float16 f16;
typedef f16 f16x8 __attribute__((ext_vector_type(8)));
typedef f16 f16x4v __attribute__((ext_vector_type(4)));
typedef float f32x4 __attribute__((ext_vector_type(4)));

#define MFMA16(a, b, c) __builtin_amdgcn_mfma_f32_16x16x32_f16(a, b, c, 0, 0, 0)

template<int C>
__device__ __forceinline__ float fdpp(float x) {
    int xi = __float_as_int(x);
    return __int_as_float(__builtin_amdgcn_update_dpp(xi, xi, C, 0xF, 0xF, true));
}
// allreduce over each 16-lane row via DPP row_ror 1,2,4,8
__device__ __forceinline__ float rrmax(float v) {
    v = fmaxf(v, fdpp<0x121>(v));
    v = fmaxf(v, fdpp<0x122>(v));
    v = fmaxf(v, fdpp<0x124>(v));
    v = fmaxf(v, fdpp<0x128>(v));
    return v;
}
__device__ __forceinline__ float rrsum(float v) {
    v += fdpp<0x121>(v);
    v += fdpp<0x122>(v);
    v += fdpp<0x124>(v);
    v += fdpp<0x128>(v);
    return v;
}

#define LGKM_BARRIER() do { \
    asm volatile("s_waitcnt lgkmcnt(0)" ::: "memory"); \
    __builtin_amdgcn_s_barrier(); \
    __builtin_amdgcn_sched_barrier(0); } while (0)

// ---------------------------------------------------------------------------
// Kernel 1: QKV projection (fp32 compute, fp16 outputs).
// q,k: [B][N][C] fp16 ; v: transposed [B][C][N] fp16
// grid (N/64, C/64, B*3), block 256
__global__ __launch_bounds__(256) void qkv_proj_kernel(
    const float* __restrict__ x,
    const float* __restrict__ wq, const float* __restrict__ bq,
    const float* __restrict__ wk, const float* __restrict__ bk,
    const float* __restrict__ wv, const float* __restrict__ bv,
    f16* __restrict__ qh, f16* __restrict__ kh, f16* __restrict__ vt16)
{
    const int p = blockIdx.z % 3;
    const int b = blockIdx.z / 3;
    const float* __restrict__ w    = (p == 0) ? wq : (p == 1) ? wk : wv;
    const float* __restrict__ bias = (p == 0) ? bq : (p == 1) ? bk : bv;

    const int on = blockIdx.x * 64;
    const int oo = blockIdx.y * 64;
    const int t  = threadIdx.x;
    const int ni = t & 15, oi = t >> 4;

    __shared__ float Xs[32][68];   // [c][n]
    __shared__ float Ws[32][68];   // [c][o]  (stored transposed)

    float acc[4][4];
    #pragma unroll
    for (int i = 0; i < 4; ++i)
        #pragma unroll
        for (int j = 0; j < 4; ++j) acc[i][j] = 0.f;

    for (int ct = 0; ct < CH; ct += 32) {
        {
            const int col = t & 63, r0 = t >> 6;
            #pragma unroll
            for (int r = 0; r < 8; ++r)
                Xs[r0 + 4*r][col] = x[((size_t)b*CH + ct + r0 + 4*r)*NSP + on + col];
        }
        {
            const int col = t & 31, r0 = t >> 5;
            #pragma unroll
            for (int r = 0; r < 8; ++r)
                Ws[col][r0 + 8*r] = w[(oo + r0 + 8*r)*CH + ct + col];
        }
        __syncthreads();
        #pragma unroll
        for (int cc = 0; cc < 32; ++cc) {
            const float4 xv  = *(const float4*)&Xs[cc][ni*4];
            const float4 wv4 = *(const float4*)&Ws[cc][oi*4];
            const float xr[4] = {xv.x, xv.y, xv.z, xv.w};
            const float wr[4] = {wv4.x, wv4.y, wv4.z, wv4.w};
            #pragma unroll
            for (int i = 0; i < 4; ++i)
                #pragma unroll
                for (int j = 0; j < 4; ++j) acc[i][j] += wr[i] * xr[j];
        }
        __syncthreads();
    }

    const float4 bb = *(const float4*)&bias[oo + oi*4];
    const float br[4] = {bb.x, bb.y, bb.z, bb.w};
    if (p < 2) {
        f16* __restrict__ out16 = (p == 0) ? qh : kh;
        #pragma unroll
        for (int j = 0; j < 4; ++j) {
            const int n = on + ni*4 + j;
            f16x4v o4 = { (f16)(acc[0][j] + br[0]), (f16)(acc[1][j] + br[1]),
                          (f16)(acc[2][j] + br[2]), (f16)(acc[3][j] + br[3]) };
            *(f16x4v*)&out16[((size_t)b*NSP + n)*CH + oo + oi*4] = o4;
        }
    } else {
        #pragma unroll
        for (int i = 0; i < 4; ++i) {
            const int o = oo + oi*4 + i;
            f16x4v o4 = { (f16)(acc[i][0] + br[i]), (f16)(acc[i][1] + br[i]),
                          (f16)(acc[i][2] + br[i]), (f16)(acc[i][3] + br[i]) };
            *(f16x4v*)&vt16[((size_t)b*CH + o)*NSP + on + ni*4] = o4;
        }
    }
}

// ---------------------------------------------------------------------------
// Kernel 2: flash attention, fp16 MFMA.
// q,k: [B][N][C] fp16; vt: [B][C][N] fp16; h: [B][N][C] fp32
// grid (N/64, B), block 256 (4 waves). Q-tile 64 rows in regs; KV tile 64 keys.
// Wave w: QK^T for keys [16w,16w+16); PV for channels [64w,64w+64).
// LDS K/V double-buffered, XOR-swizzled (byte ^= (row&7)<<4) both on the
// pre-swizzled global_load_lds source and the ds_read_b128 fragment reads.
__global__ __launch_bounds__(256, 1) void attn_kernel(
    const f16* __restrict__ qp, const f16* __restrict__ kp,
    const f16* __restrict__ vtp, float* __restrict__ h)
{
    __shared__ __align__(16) char KTs[65536];   // [2][64 keys][256 ch] fp16 swz
    __shared__ __align__(16) char VTs[65536];   // [2][256 ch][64 keys] fp16 swz
    __shared__ __align__(16) char PSs[9216];    // P [64 rows][72 f16] swz
    __shared__ float RED[64][4];                // cross-wave reduce [row][wave]

    const int t    = threadIdx.x;
    const int w    = t >> 6;
    const int lane = t & 63;
    const int m    = lane & 15;
    const int q4   = lane >> 4;
    const int b    = blockIdx.y;
    const int qn0  = blockIdx.x * 64;

    // ---- Q fragments: rows rb*16+m, k-chunk kc*32 + q4*8 ----
    const f16* qb = qp + ((size_t)b*NSP + qn0)*CH;
    f16x8 qa[4][8];
    #pragma unroll
    for (int rb = 0; rb < 4; ++rb)
        #pragma unroll
        for (int kc = 0; kc < 8; ++kc)
            qa[rb][kc] = *(const f16x8*)(qb + (rb*16 + m)*CH + kc*32 + q4*8);

    const char* kgb = (const char*)(kp + (size_t)b*NSP*CH);
    const char* vgb = (const char*)(vtp + (size_t)b*CH*NSP);

    f32x4 acc[4][4] = {};
    float mold[4][4], lw[4][4];
    #pragma unroll
    for (int rb = 0; rb < 4; ++rb)
        #pragma unroll
        for (int c = 0; c < 4; ++c) { mold[rb][c] = -3.0e38f; lw[rb][c] = 0.f; }

    // wave-local staging: wave w stages exactly the LDS rows it later reads
    auto stage = [&](int buf, int kt) {
        const char* kg = kgb + (size_t)kt * (CH*2);
        const char* vg = vgb + (size_t)kt * 2;
        char* kl = KTs + buf*32768 + w*8192;
        char* vl = VTs + buf*32768 + w*8192;
        #pragma unroll
        for (int i = 0; i < 8; ++i) {
            const int krow = w*16 + i*2 + (lane >> 5);
            const int ksrc = krow*512 + (((lane & 31)*16) ^ ((krow & 7) << 4));
            __builtin_amdgcn_global_load_lds(
                (const __attribute__((address_space(1))) unsigned int*)(kg + ksrc),
                (__attribute__((address_space(3))) unsigned int*)(kl + i*1024), 16, 0, 0);
            const int vrow = w*64 + i*8 + (lane >> 3);
            const int vsrc = vrow*8192 + (((lane & 7)*16) ^ ((vrow & 7) << 4));
            __builtin_amdgcn_global_load_lds(
                (const __attribute__((address_space(1))) unsigned int*)(vg + vsrc),
                (__attribute__((address_space(3))) unsigned int*)(vl + i*1024), 16, 0, 0);
        }
    };

    stage(0, 0);

    for (int tt = 0; tt < 64; ++tt) {
        const int buf = tt & 1;
        const char* KTb = KTs + buf*32768;
        const char* VTb = VTs + buf*32768;

        asm volatile("s_waitcnt vmcnt(0)" ::: "memory");   // own staged tile ready
        __builtin_amdgcn_sched_barrier(0);
        if (tt < 63) stage(buf ^ 1, (tt + 1)*64);          // prefetch next tile

        // ---- S = Q K^T : wave's 16 keys, 64 q-rows ----
        f32x4 s[4] = {};
        const int krow = w*16 + m;
        #pragma unroll
        for (int kc = 0; kc < 8; ++kc) {
            const f16x8 kb = *(const f16x8*)(KTb + krow*512 +
                                 ((kc*64 + q4*16) ^ ((m & 7) << 4)));
            s[0] = MFMA16(qa[0][kc], kb, s[0]);
            s[1] = MFMA16(qa[1][kc], kb, s[1]);
            s[2] = MFMA16(qa[2][kc], kb, s[2]);
            s[3] = MFMA16(qa[3][kc], kb, s[3]);
        }

        // ---- wave-local row max -> cross-wave via LDS ----
        #pragma unroll
        for (int rb = 0; rb < 4; ++rb)
            #pragma unroll
            for (int c = 0; c < 4; ++c) {
                const float wm = rrmax(s[rb][c]);
                if (m == c) RED[rb*16 + q4*4 + c][w] = wm;
            }
        LGKM_BARRIER();

        float p[4][4];
        #pragma unroll
        for (int rb = 0; rb < 4; ++rb)
            #pragma unroll
            for (int c = 0; c < 4; ++c) {
                const f32x4 r4 = *(const f32x4*)&RED[rb*16 + q4*4 + c][0];
                const float tmax = fmaxf(fmaxf(r4.x, r4.y), fmaxf(r4.z, r4.w));
                const float nm  = fmaxf(mold[rb][c], tmax);
                const float scf = __expf(mold[rb][c] - nm);
                mold[rb][c] = nm;
                const float pv = __expf(s[rb][c] - nm);
                p[rb][c] = pv;
                lw[rb][c] = lw[rb][c]*scf + rrsum(pv);
                acc[rb][0][c] *= scf;
                acc[rb][1][c] *= scf;
                acc[rb][2][c] *= scf;
                acc[rb][3][c] *= scf;
            }

        // ---- P -> LDS (fp16, swizzled), rows=q-rows cols=keys ----
        #pragma unroll
        for (int rb = 0; rb < 4; ++rb)
            #pragma unroll
            for (int c = 0; c < 4; ++c) {
                const int rowp = rb*16 + q4*4 + c;
                *(f16*)(PSs + rowp*144 +
                        (((w*16 + m)*2) ^ ((rowp & 7) << 4))) = (f16)p[rb][c];
            }
        LGKM_BARRIER();

        // ---- H += P V : wave's 64 channels, all 64 q-rows ----
        #pragma unroll
        for (int kc2 = 0; kc2 < 2; ++kc2) {
            f16x8 pa[4];
            #pragma unroll
            for (int rb = 0; rb < 4; ++rb)
                pa[rb] = *(const f16x8*)(PSs + (rb*16 + m)*144 +
                             ((kc2*64 + q4*16) ^ ((m & 7) << 4)));
            #pragma unroll
            for (int cf = 0; cf < 4; ++cf) {
                const int rowv = w*64 + cf*16 + m;
                const f16x8 vb = *(const f16x8*)(VTb + rowv*128 +
                                     ((kc2*64 + q4*16) ^ ((m & 7) << 4)));
                acc[0][cf] = MFMA16(pa[0], vb, acc[0][cf]);
                acc[1][cf] = MFMA16(pa[1], vb, acc[1][cf]);
                acc[2][cf] = MFMA16(pa[2], vb, acc[2][cf]);
                acc[3][cf] = MFMA16(pa[3], vb, acc[3][cf]);
            }
        }
    }

    // ---- reduce l across waves, normalize, store h ----
    #pragma unroll
    for (int rb = 0; rb < 4; ++rb)
        #pragma unroll
        for (int c = 0; c < 4; ++c)
            if (m == c) RED[rb*16 + q4*4 + c][w] = lw[rb][c];
    LGKM_BARRIER();
    float* hb = h + ((size_t)b*NSP + qn0)*CH;
    #pragma unroll
    for (int rb = 0; rb < 4; ++rb)
        #pragma unroll
        for (int c = 0; c < 4; ++c) {
            const int row = rb*16 + q4*4 + c;
            const f32x4 r4 = *(const f32x4*)&RED[row][0];
            const float li = 1.f / (r4.x + r4.y + r4.z + r4.w);
            #pragma unroll
            for (int cf = 0; cf < 4; ++cf)
                hb[(size_t)row*CH + w*64 + cf*16 + m] = acc[rb][cf][c] * li;
        }
}

// ---------------------------------------------------------------------------
// Kernel 3: y[b][o][n] = sum_c wo[o][c]*h[b][n][c] + bo[o] + x[b][o][n]
// grid (N/64, C/64, B), block 256
__global__ __launch_bounds__(256) void oproj_kernel(
    const float* __restrict__ h, const float* __restrict__ wo,
    const float* __restrict__ bo, const float* __restrict__ x,
    float* __restrict__ y, float* __restrict__ stats)
{
    const int b  = blockIdx.z;
    const int on = blockIdx.x * 64;
    const int oo = blockIdx.y * 64;
    const int t  = threadIdx.x;
    const int ni = t & 15, oi = t >> 4;

    __shared__ float Hs[32][68];
    __shared__ float Ws[32][68];

    float acc[4][4];
    #pragma unroll
    for (int i = 0; i < 4; ++i)
        #pragma unroll
        for (int j = 0; j < 4; ++j) acc[i][j] = 0.f;

    for (int ct = 0; ct < CH; ct += 32) {
        {
            const int col = t & 31, r0 = t >> 5;
            #pragma unroll
            for (int rr = 0; rr < 8; ++rr)
                Hs[col][r0 + 8*rr] = h[((size_t)b*NSP + on + r0 + 8*rr)*CH + ct + col];
        }
        {
            const int col = t & 31, r0 = t >> 5;
            #pragma unroll
            for (int rr = 0; rr < 8; ++rr)
                Ws[col][r0 + 8*rr] = wo[(oo + r0 + 8*rr)*CH + ct + col];
        }
        __syncthreads();
        #pragma unroll
        for (int cc = 0; cc < 32; ++cc) {
            const float4 hv  = *(const float4*)&Hs[cc][ni*4];
            const float4 wv4 = *(const float4*)&Ws[cc][oi*4];
            const float hr[4] = {hv.x, hv.y, hv.z, hv.w};
            const float wr[4] = {wv4.x, wv4.y, wv4.z, wv4.w};
            #pragma unroll
            for (int i = 0; i < 4; ++i)
                #pragma unroll
                for (int j = 0; j < 4; ++j) acc[i][j] += wr[i] * hr[j];
        }
        __syncthreads();
    }

    float s = 0.f, sq = 0.f;
    #pragma unroll
    for (int i = 0; i < 4; ++i) {
        const int o = oo + oi*4 + i;
        const float bb = bo[o];
        const size_t base = ((size_t)b*CH + o)*NSP + on + ni*4;
        const float4 xv = *(const float4*)&x[base];
        float4 o4;
        o4.x = acc[i][0] + bb + xv.x;
        o4.y = acc[i][1] + bb + xv.y;
        o4.z = acc[i][2] + bb + xv.z;
        o4.w = acc[i][3] + bb + xv.w;
        *(float4*)&y[base] = o4;
        s  += o4.x + o4.y + o4.z + o4.w;
        sq += o4.x*o4.x + o4.y*o4.y + o4.z*o4.z + o4.w*o4.w;
    }
    #pragma unroll
    for (int off = 8; off > 0; off >>= 1) {
        s  += __shfl_down(s, off, 16);
        sq += __shfl_down(sq, off, 16);
    }
    if (ni == 0) {
        const int gg = (oo >> 3) + (oi >> 1);
        atomicAdd(&stats[((size_t)b*NGRP + gg)*2 + 0], s);
        atomicAdd(&stats[((size_t)b*NGRP + gg)*2 + 1], sq);
    }
}

// ---------------------------------------------------------------------------
// Kernel 4: GroupNorm finalize + swish, in-place on y (= d_out).
__global__ __launch_bounds__(256) void gn_swish_kernel(
    float* __restrict__ y, const float* __restrict__ stats,
    const float* __restrict__ gamma, const float* __restrict__ beta)
{
    const int bg = blockIdx.x;
    const int b = bg >> 5, g = bg & 31;
    const float s  = stats[bg*2 + 0];
    const float sq = stats[bg*2 + 1];
    const float inv_n = 1.f / 32768.f;
    const float mu  = s * inv_n;
    const float var = sq * inv_n - mu*mu;
    const float rs  = rsqrtf(var + EPS_GN);
    float* __restrict__ base = y + ((size_t)b*CH + g*8)*NSP;
    const int t = threadIdx.x;
    #pragma unroll 4
    for (int it = 0; it < 32; ++it) {
        const int qi = t + 256*it;
        const int o8 = qi >> 10;
        const float ga = gamma[g*8 + o8] * rs;
        const float be = beta[g*8 + o8];
        float4 yv = *(const float4*)&base[qi*4];
        float yn;
        yn = (yv.x - mu)*ga + be; yv.x = yn / (1.f + __expf(-yn));
        yn = (yv.y - mu)*ga + be; yv.y = yn / (1.f + __expf(-yn));
        yn = (yv.z - mu)*ga + be; yv.z = yn / (1.f + __expf(-yn));
        yn = (yv.w - mu)*ga + be; yv.w = yn / (1.f + __expf(-yn));
        *(float4*)&base[qi*4] = yv;
    }
}

// ---------------------------------------------------------------------------
extern "C" void kernel_launch(void* const* d_in, const int* in_sizes, int n_in,
                              void* d_out, int out_size, void* d_ws, size_t ws_size,
                              hipStream_t stream)
{
    const float* x     = (const float*)d_in[0];
    const float* wq    = (const float*)d_in[1];
    const float* bq    = (const float*)d_in[2];
    const float* wk    = (const float*)d_in[3];
    const float* bk    = (const float*)d_in[4];
    const float* wv    = (const float*)d_in[5];
    const float* bv    = (const float*)d_in[6];
    const float* wo    = (const float*)d_in[7];
    const float* bo    = (const float*)d_in[8];
    const float* gamma = (const float*)d_in[9];
    const float* beta  = (const float*)d_in[10];

    float* out = (float*)d_out;
    float* ws  = (float*)d_ws;
    // ws layout (float units): qh[2M] kh[2M] vt[2M] (fp16 pairs) | h f32 [4.19M] | stats
    f16*   qh    = (f16*)ws;
    f16*   kh    = (f16*)(ws + 2097152);
    f16*   vt    = (f16*)(ws + 4194304);
    float* hbuf  = ws + 6291456;
    float* stats = ws + 10485760;

    hipMemsetAsync(stats, 0, BATCH*NGRP*2*sizeof(float), stream);

    dim3 g1(NSP/64, CH/64, BATCH*3);
    qkv_proj_kernel<<<g1, 256, 0, stream>>>(x, wq, bq, wk, bk, wv, bv, qh, kh, vt);

    dim3 g2(NSP/64, BATCH);
    attn_kernel<<<g2, 256, 0, stream>>>(qh, kh, vt, hbuf);

    dim3 g3(NSP/64, CH/64, BATCH);
    oproj_kernel<<<g3, 256, 0, stream>>>(hbuf, wo, bo, x, out, stats);

    gn_swish_kernel<<<BATCH*NGRP, 256, 0, stream>>>(out, stats, gamma, beta);
}